// Round 5
// baseline (390.358 us; speedup 1.0000x reference)
//
#include <hip/hip_runtime.h>

#define NN 8192     // N_U == N_V
#define DIM 64
#define NR 5

typedef __attribute__((ext_vector_type(8))) short short8;
typedef __attribute__((ext_vector_type(4))) float f32x4;

__device__ inline unsigned short f2bf(float x) {
    unsigned u = __float_as_uint(x);
    return (unsigned short)((u + 0x7FFFu + ((u >> 16) & 1u)) >> 16);
}

// P fragment linear index (shorts) for (r, k, o).
// Bijection within a ktile: g = (k>>3)&3, j = k&7 (k = g*8 + j). The A-mask
// build uses the same (g,j)->k map, so the permutation cancels in the MFMA.
// linear = r*(256*2048) + ktile*2048 + n*512 + lane*8 + j,
//   lane = g*16 + (o&15), n = o>>4.
__device__ inline int pfrag_idx(int r, int k, int o) {
    int ktile = k >> 5;
    int g     = (k >> 3) & 3;
    int j     = k & 7;
    int lane  = g * 16 + (o & 15);
    int n     = o >> 4;
    return ((r * 256 + ktile) * 4 + n) * 512 + lane * 8 + j;
}

// ---------------- P precompute: P[r][v][o] = sum_f feat[v][f] * W[r][f][o] ----
__global__ __launch_bounds__(256) void precompute_P(
    const float* __restrict__ u_feat, const float* __restrict__ v_feat,
    const float* __restrict__ w_u, const float* __restrict__ w_v,
    unsigned short* __restrict__ p_u, unsigned short* __restrict__ p_v)
{
    int wid  = (blockIdx.x * blockDim.x + threadIdx.x) >> 6;
    int lane = threadIdx.x & 63;
    const int tasks = 2 * NR * (NN / 32);
    if (wid >= tasks) return;
    int dir  = wid / (NR * (NN / 32));
    int rem  = wid % (NR * (NN / 32));
    int r    = rem / (NN / 32);
    int v0   = (rem % (NN / 32)) * 32;

    const float* feat = dir ? u_feat : v_feat;
    const float* w    = dir ? w_v : w_u;
    unsigned short* dst = dir ? p_v : p_u;

    float wreg[DIM];
#pragma unroll
    for (int f = 0; f < DIM; ++f) wreg[f] = w[(r * DIM + f) * DIM + lane];

    for (int v = v0; v < v0 + 32; ++v) {
        float x = feat[(size_t)v * DIM + lane];
        float acc = 0.f;
#pragma unroll
        for (int f = 0; f < DIM; ++f) acc += __shfl(x, f) * wreg[f];
        dst[pfrag_idx(r, v, lane)] = f2bf(acc);
    }
}

// ---------------- masked GEMM, one direction, atomic-free ----------------
// Block owns 16 output rows x full K=8192. Wave w handles ktiles w, w+8, ...
// DIR=0: out_u rows = u, k = v (row-major int4 loads).
// DIR=1: out_v rows = v, k = u (8 stride-NN dword loads; 64B line = 16 cols).
// Degrees counted inline; 1/deg + ReLU fused into the epilogue. No atomics.
template <int DIR>
__global__ __launch_bounds__(512, 4) void gemm_dir(
    const int* __restrict__ adj, const unsigned short* __restrict__ pfrag,
    float* __restrict__ outp)
{
    __shared__ float redf[4][16][66];   // +2 pad: conflict-light tree stores
    __shared__ int   redd[8][16];

    const int tid  = threadIdx.x;
    const int lane = tid & 63;
    const int wv   = tid >> 6;
    const int row  = lane & 15;         // A-operand M row / C col
    const int g    = lane >> 4;         // k lane-group
    const int b0   = blockIdx.x * 16;

    f32x4 acc[4];
#pragma unroll
    for (int n = 0; n < 4; ++n) acc[n] = (f32x4){0.f, 0.f, 0.f, 0.f};
    int dcnt = 0;

#pragma unroll 2
    for (int kt = wv; kt < NN / 32; kt += 8) {
        int a[8];
        if (DIR == 0) {
            const int* ap = adj + (b0 + row) * NN + kt * 32 + g * 8;
            int4 x = *(const int4*)ap;
            int4 y = *(const int4*)(ap + 4);
            a[0] = x.x; a[1] = x.y; a[2] = x.z; a[3] = x.w;
            a[4] = y.x; a[5] = y.y; a[6] = y.z; a[7] = y.w;
        } else {
            const int* ap = adj + (kt * 32 + g * 8) * NN + b0 + row;
#pragma unroll
            for (int j = 0; j < 8; ++j) a[j] = ap[j * NN];
        }
#pragma unroll
        for (int j = 0; j < 8; ++j) dcnt += (a[j] != 0);

        const int kb = kt << 11;        // kt*2048 shorts
#pragma unroll
        for (int r = 0; r < NR; ++r) {
            short8 am;
#pragma unroll
            for (int j = 0; j < 8; ++j)
                am[j] = (short)(a[j] == r + 1 ? 0x3F80 : 0);
            const unsigned short* pb = pfrag + r * (256 * 2048) + kb + (lane << 3);
#pragma unroll
            for (int n = 0; n < 4; ++n) {
                short8 bf = *(const short8*)(pb + (n << 9));
                acc[n] = __builtin_amdgcn_mfma_f32_16x16x32_bf16(am, bf, acc[n], 0, 0, 0);
            }
        }
    }

    // ---- degree: fold k lane-groups, park per-wave row counts ----
    dcnt += __shfl_xor(dcnt, 16);
    dcnt += __shfl_xor(dcnt, 32);
    if (lane < 16) redd[wv][lane] = dcnt;

    // ---- accumulator tree reduce: 8 -> 4 -> 2 -> 1 waves ----
    if (wv >= 4) {
#pragma unroll
        for (int n = 0; n < 4; ++n)
#pragma unroll
            for (int q = 0; q < 4; ++q)
                redf[wv - 4][g * 4 + q][n * 16 + row] = acc[n][q];
    }
    __syncthreads();
    if (wv < 4) {
#pragma unroll
        for (int n = 0; n < 4; ++n)
#pragma unroll
            for (int q = 0; q < 4; ++q)
                acc[n][q] += redf[wv][g * 4 + q][n * 16 + row];
    }
    __syncthreads();
    if (wv == 2 || wv == 3) {
#pragma unroll
        for (int n = 0; n < 4; ++n)
#pragma unroll
            for (int q = 0; q < 4; ++q)
                redf[wv - 2][g * 4 + q][n * 16 + row] = acc[n][q];
    }
    __syncthreads();
    if (wv < 2) {
#pragma unroll
        for (int n = 0; n < 4; ++n)
#pragma unroll
            for (int q = 0; q < 4; ++q)
                acc[n][q] += redf[wv][g * 4 + q][n * 16 + row];
    }
    __syncthreads();
    if (wv == 1) {
#pragma unroll
        for (int n = 0; n < 4; ++n)
#pragma unroll
            for (int q = 0; q < 4; ++q)
                redf[0][g * 4 + q][n * 16 + row] = acc[n][q];
    }
    __syncthreads();

    // ---- wave 0: final add, 1/deg, ReLU, store (C: col=lane&15, row=g*4+q) ----
    if (wv == 0) {
#pragma unroll
        for (int q = 0; q < 4; ++q) {
            int r4 = g * 4 + q;
            int dsum = 0;
#pragma unroll
            for (int w = 0; w < 8; ++w) dsum += redd[w][r4];
            float s = dsum ? 1.f / (float)dsum : 0.f;
#pragma unroll
            for (int n = 0; n < 4; ++n) {
                float v = (acc[n][q] + redf[0][r4][n * 16 + row]) * s;
                outp[(b0 + r4) * DIM + n * 16 + row] = v > 0.f ? v : 0.f;
            }
        }
    }
}

extern "C" void kernel_launch(void* const* d_in, const int* in_sizes, int n_in,
                              void* d_out, int out_size, void* d_ws, size_t ws_size,
                              hipStream_t stream)
{
    const int*   adj = (const int*)d_in[0];
    const float* uf  = (const float*)d_in[1];
    const float* vf  = (const float*)d_in[2];
    const float* wu  = (const float*)d_in[3];
    const float* wv  = (const float*)d_in[4];
    float* outp = (float*)d_out;

    unsigned char* ws = (unsigned char*)d_ws;
    const size_t P_BYTES = (size_t)NR * (NN / 32) * 4 * 64 * 8 * 2;  // 5,242,880
    unsigned short* p_u = (unsigned short*)ws;
    unsigned short* p_v = (unsigned short*)(ws + P_BYTES);

    precompute_P<<<640, 256, 0, stream>>>(uf, vf, wu, wv, p_u, p_v);

    gemm_dir<0><<<NN / 16, 512, 0, stream>>>(adj, p_u, outp);
    gemm_dir<1><<<NN / 16, 512, 0, stream>>>(adj, p_v, outp + (size_t)NN * DIM);
}